// Round 5
// baseline (576.493 us; speedup 1.0000x reference)
//
#include <hip/hip_runtime.h>
#include <hip/hip_bf16.h>

// MHSA_69621419869026 — p=4 sketch linear attention, MI355X gfx950.
// Round 5: sketch folded into the projection GEMM via weight composition:
//   u = (gamma*(x@W+b)+beta)@G  ==  x@(gamma*W@G) + c
// One fused MFMA GEMM x[32768,512] @ WC[512,2560] with phi epilogue
// (pair columns interleaved; shfl_xor(1) pairs u1/u2). Outputs phi_q/phi_k/v
// in bf16. Sketch kernels and fp32 q/k round-trip eliminated.
// Dims: B=4 S=8192 D=512 H=8 HD=R=64, N=B*S=32768.

#define SEQ 8192

typedef __attribute__((ext_vector_type(8))) short bf16x8;
typedef __attribute__((ext_vector_type(4))) float f32x4;

__device__ __forceinline__ unsigned short f2b(float f) {
    union { float f; unsigned int i; } v; v.f = f;
    unsigned int r = v.i + 0x7fffu + ((v.i >> 16) & 1u);   // RNE
    return (unsigned short)(r >> 16);
}
__device__ __forceinline__ float b2f(unsigned short u) {
    union { unsigned int i; float f; } v; v.i = ((unsigned int)u) << 16; return v.f;
}

#if __has_builtin(__builtin_amdgcn_global_load_lds)
#define ASYNC_CP 1
#endif

__device__ __forceinline__ void cp16(const unsigned short* g, unsigned short* l) {
#ifdef ASYNC_CP
    __builtin_amdgcn_global_load_lds(
        (const __attribute__((address_space(1))) unsigned int*)g,
        (__attribute__((address_space(3))) unsigned int*)l, 16, 0, 0);
#endif
}

// ---------------- pre-pass: x fp32 -> bf16 (RNE) ----------------------------
__global__ __launch_bounds__(256) void convert_x(
    const float* __restrict__ x, unsigned short* __restrict__ xb)
{
    size_t i = ((size_t)blockIdx.x * 256 + threadIdx.x) * 8;
    float4 a = *(const float4*)&x[i];
    float4 b = *(const float4*)&x[i + 4];
    ushort4 o1 = { f2b(a.x), f2b(a.y), f2b(a.z), f2b(a.w) };
    ushort4 o2 = { f2b(b.x), f2b(b.y), f2b(b.z), f2b(b.w) };
    *(ushort4*)&xb[i]     = o1;
    *(ushort4*)&xb[i + 4] = o2;
}

// ---------------- pre-pass: Wv/Wp fp32 [k][n] -> bf16 [n][k] -----------------
// z=0: Wv -> WTf + 2048*512 (v section of fused B); z=1: Wp -> WTp.
__global__ __launch_bounds__(256) void convert_wT(
    const float* __restrict__ Wv, const float* __restrict__ Wp,
    unsigned short* __restrict__ WTf, unsigned short* __restrict__ WTp)
{
    const int z = blockIdx.z;
    const float* W = (z == 0) ? Wv : Wp;
    unsigned short* O = (z == 0) ? (WTf + (size_t)2048 * 512) : WTp;
    __shared__ float t[32][33];
    const int tid = threadIdx.x;
    const int tx = tid & 31, ty = tid >> 5;
    const int k0 = blockIdx.x * 32, n0 = blockIdx.y * 32;
    #pragma unroll
    for (int i = 0; i < 4; ++i)
        t[ty + 8 * i][tx] = W[(size_t)(k0 + ty + 8 * i) * 512 + n0 + tx];
    __syncthreads();
    #pragma unroll
    for (int i = 0; i < 4; ++i)
        O[(size_t)(n0 + ty + 8 * i) * 512 + k0 + tx] = f2b(t[tx][ty + 8 * i]);
}

// ---------------- weight composition: WC = gamma * W_z[:,h-block] @ G --------
// grid 33. blocks 0..31: (zz = bi>>4: 0=q 1=k, h = (bi>>1)&7, p = bi&1)
//   WTf[jc][k] = gamma * sum_j W[k][h*64+j] * G[j][rr],  jc = zz*1024 + h*128 + rr*2 + p
//   cvec[jc]   = gamma * sum_j b[h*64+j] * G[j][rr] + beta * sum_j G[j][rr]
// block 32: cvec[2048+n] = bv[n].
__global__ __launch_bounds__(256) void precompute_wc(
    const float* __restrict__ Wq, const float* __restrict__ bq,
    const float* __restrict__ Wk, const float* __restrict__ bk,
    const float* __restrict__ bv,
    const float* __restrict__ gq, const float* __restrict__ bbq,
    const float* __restrict__ gk, const float* __restrict__ bbk,
    const float* __restrict__ qG1, const float* __restrict__ qG2,
    const float* __restrict__ kG1, const float* __restrict__ kG2,
    unsigned short* __restrict__ WTf, float* __restrict__ cvec)
{
    const int bi = blockIdx.x;
    const int tid = threadIdx.x;
    if (bi == 32) {
        for (int i = tid; i < 512; i += 256) cvec[2048 + i] = bv[i];
        return;
    }
    const int zz = bi >> 4, h = (bi >> 1) & 7, p = bi & 1;
    const float* W    = zz ? Wk : Wq;
    const float* bias = zz ? bk : bq;
    const float* G    = zz ? (p ? kG2 : kG1) : (p ? qG2 : qG1);
    const float  gamma = zz ? gk[0] : gq[0];
    const float  beta  = zz ? bbk[0] : bbq[0];

    __shared__ float Gs[64][65];
    for (int i = tid; i < 4096; i += 256) Gs[i >> 6][i & 63] = G[i];
    __syncthreads();

    const int rr = tid & 63, kg = tid >> 6;
    const int jc = zz * 1024 + h * 128 + rr * 2 + p;
    for (int k = kg; k < 512; k += 4) {
        float s = 0.f;
        const float* wrow = &W[(size_t)k * 512 + h * 64];
        #pragma unroll 8
        for (int j = 0; j < 64; ++j) s = fmaf(wrow[j], Gs[j][rr], s);
        WTf[(size_t)jc * 512 + k] = f2b(gamma * s);
    }
    if (kg == 0) {
        float cb = 0.f, cg = 0.f;
        #pragma unroll 8
        for (int j = 0; j < 64; ++j) {
            cb = fmaf(bias[h * 64 + j], Gs[j][rr], cb);
            cg += Gs[j][rr];
        }
        cvec[jc] = gamma * cb + beta * cg;
    }
}

// ---------------- fused MFMA GEMM: U = x @ WC, phi/v epilogue ----------------
// grid (256 token-tiles, 20 j-tiles). 128x128 tile, 4 waves.
// jc in [0,1024): phi_q pairs; [1024,2048): phi_k pairs; [2048,2560): v.
__global__ __launch_bounds__(256) void gemm_mfma_fused(
    const unsigned short* __restrict__ xb,
    const unsigned short* __restrict__ WTf,
    const float* __restrict__ cvec,
    unsigned short* __restrict__ PHIQ, unsigned short* __restrict__ PHIK,
    unsigned short* __restrict__ Vb)
{
    __shared__ __align__(16) unsigned short As[128 * 32];
    __shared__ __align__(16) unsigned short Bs[128 * 32];

    const int tid = threadIdx.x;
    const int w = tid >> 6, lane = tid & 63;
    const int n0 = blockIdx.x * 128;
    const int j0 = blockIdx.y * 128;
    const int wr = w >> 1, wc = w & 1;

    const int r0 = w * 32 + (lane >> 2);
    const int kq = (lane & 3) * 8;
    const unsigned short* gA = &xb[(size_t)(n0 + r0) * 512 + kq];
    const unsigned short* gB = &WTf[(size_t)(j0 + r0) * 512 + kq];
    unsigned short* lA = &As[(w * 32) * 32];
    unsigned short* lB = &Bs[(w * 32) * 32];

    f32x4 acc[4][4];
    #pragma unroll
    for (int i = 0; i < 4; ++i)
        #pragma unroll
        for (int j = 0; j < 4; ++j) { acc[i][j] = (f32x4){0.f, 0.f, 0.f, 0.f}; }

    for (int k0 = 0; k0 < 512; k0 += 32) {
        __syncthreads();
#ifdef ASYNC_CP
        cp16(gA + k0, lA);
        cp16(gA + 16 * 512 + k0, lA + 16 * 32);
        cp16(gB + k0, lB);
        cp16(gB + 16 * 512 + k0, lB + 16 * 32);
#else
        { uint4 v = *(const uint4*)(gA + k0);            *(uint4*)(lA + (size_t)lane * 8) = v; }
        { uint4 v = *(const uint4*)(gA + 16 * 512 + k0); *(uint4*)(lA + 16 * 32 + (size_t)lane * 8) = v; }
        { uint4 v = *(const uint4*)(gB + k0);            *(uint4*)(lB + (size_t)lane * 8) = v; }
        { uint4 v = *(const uint4*)(gB + 16 * 512 + k0); *(uint4*)(lB + 16 * 32 + (size_t)lane * 8) = v; }
#endif
        __syncthreads();

        bf16x8 af[4], bfr[4];
        #pragma unroll
        for (int i = 0; i < 4; ++i) {
            af[i]  = *(const bf16x8*)&As[(wr * 64 + i * 16 + (lane & 15)) * 32 + (lane >> 4) * 8];
            bfr[i] = *(const bf16x8*)&Bs[(wc * 64 + i * 16 + (lane & 15)) * 32 + (lane >> 4) * 8];
        }
        #pragma unroll
        for (int mi = 0; mi < 4; ++mi)
            #pragma unroll
            for (int ni = 0; ni < 4; ++ni)
                acc[mi][ni] = __builtin_amdgcn_mfma_f32_16x16x32_bf16(
                    af[mi], bfr[ni], acc[mi][ni], 0, 0, 0);
    }

    // epilogue. jcol parity == lane&1; a 128-col tile sits in exactly one group
    // (q-head / k-head / v) so branches are wave-uniform.
    #pragma unroll
    for (int ni = 0; ni < 4; ++ni) {
        const int jcol = j0 + wc * 64 + ni * 16 + (lane & 15);
        const float cv = cvec[jcol];
        if (jcol < 2048) {                       // phi path
            const int zq = jcol >> 10;           // 0 = q, 1 = k
            const int lc = jcol & 1023;
            const int h = lc >> 7, rr = (lc >> 1) & 63;
            unsigned short* dst = zq ? PHIK : PHIQ;
            #pragma unroll
            for (int mi = 0; mi < 4; ++mi) {
                #pragma unroll
                for (int r = 0; r < 4; ++r) {
                    float u = acc[mi][ni][r] + cv;
                    float up = __shfl_xor(u, 1);
                    float hh = 0.125f * u * up;
                    float phi = hh * hh;
                    if ((lane & 1) == 0) {
                        const int t = n0 + wr * 64 + mi * 16 + (lane >> 4) * 4 + r;
                        const int b = t >> 13, s = t & (SEQ - 1);
                        dst[((size_t)(b * 8 + h) * SEQ + s) * 64 + rr] = f2b(phi);
                    }
                }
            }
        } else {                                 // v path
            const int n = jcol - 2048;
            const int h = n >> 6, hd = n & 63;
            #pragma unroll
            for (int mi = 0; mi < 4; ++mi) {
                #pragma unroll
                for (int r = 0; r < 4; ++r) {
                    const int t = n0 + wr * 64 + mi * 16 + (lane >> 4) * 4 + r;
                    const int b = t >> 13, s = t & (SEQ - 1);
                    Vb[((size_t)(b * 8 + h) * SEQ + s) * 64 + hd] =
                        f2b(acc[mi][ni][r] + cv);
                }
            }
        }
    }
}

// ---------------- bf16 MFMA GEMM: final projection ---------------------------
__global__ __launch_bounds__(256) void gemm_mfma_final(
    const unsigned short* __restrict__ Ab,
    const unsigned short* __restrict__ WTp,
    const float* __restrict__ bias, float* __restrict__ out)
{
    __shared__ __align__(16) unsigned short As[128 * 32];
    __shared__ __align__(16) unsigned short Bs[128 * 32];

    const int tid = threadIdx.x;
    const int w = tid >> 6, lane = tid & 63;
    const int n0 = blockIdx.x * 128;
    const int j0 = blockIdx.y * 128;
    const int wr = w >> 1, wc = w & 1;

    const int r0 = w * 32 + (lane >> 2);
    const int kq = (lane & 3) * 8;
    const unsigned short* gA = &Ab[(size_t)(n0 + r0) * 512 + kq];
    const unsigned short* gB = &WTp[(size_t)(j0 + r0) * 512 + kq];
    unsigned short* lA = &As[(w * 32) * 32];
    unsigned short* lB = &Bs[(w * 32) * 32];

    f32x4 acc[4][4];
    #pragma unroll
    for (int i = 0; i < 4; ++i)
        #pragma unroll
        for (int j = 0; j < 4; ++j) { acc[i][j] = (f32x4){0.f, 0.f, 0.f, 0.f}; }

    for (int k0 = 0; k0 < 512; k0 += 32) {
        __syncthreads();
#ifdef ASYNC_CP
        cp16(gA + k0, lA);
        cp16(gA + 16 * 512 + k0, lA + 16 * 32);
        cp16(gB + k0, lB);
        cp16(gB + 16 * 512 + k0, lB + 16 * 32);
#else
        { uint4 v = *(const uint4*)(gA + k0);            *(uint4*)(lA + (size_t)lane * 8) = v; }
        { uint4 v = *(const uint4*)(gA + 16 * 512 + k0); *(uint4*)(lA + 16 * 32 + (size_t)lane * 8) = v; }
        { uint4 v = *(const uint4*)(gB + k0);            *(uint4*)(lB + (size_t)lane * 8) = v; }
        { uint4 v = *(const uint4*)(gB + 16 * 512 + k0); *(uint4*)(lB + 16 * 32 + (size_t)lane * 8) = v; }
#endif
        __syncthreads();

        bf16x8 af[4], bfr[4];
        #pragma unroll
        for (int i = 0; i < 4; ++i) {
            af[i]  = *(const bf16x8*)&As[(wr * 64 + i * 16 + (lane & 15)) * 32 + (lane >> 4) * 8];
            bfr[i] = *(const bf16x8*)&Bs[(wc * 64 + i * 16 + (lane & 15)) * 32 + (lane >> 4) * 8];
        }
        #pragma unroll
        for (int mi = 0; mi < 4; ++mi)
            #pragma unroll
            for (int ni = 0; ni < 4; ++ni)
                acc[mi][ni] = __builtin_amdgcn_mfma_f32_16x16x32_bf16(
                    af[mi], bfr[ni], acc[mi][ni], 0, 0, 0);
    }

    #pragma unroll
    for (int ni = 0; ni < 4; ++ni) {
        const int jcol = j0 + wc * 64 + ni * 16 + (lane & 15);
        const float bvv = bias[jcol];
        #pragma unroll
        for (int mi = 0; mi < 4; ++mi) {
            #pragma unroll
            for (int r = 0; r < 4; ++r) {
                const int t = n0 + wr * 64 + mi * 16 + (lane >> 4) * 4 + r;
                out[(size_t)t * 512 + jcol] = acc[mi][ni][r] + bvv;
            }
        }
    }
}

// ---------------- kv = phi_k^T @ v, ksum (split-S partials), 4x4 tiled -------
// bf16 inputs staged -> f32 LDS. grid (32 bh, 32 chunks of 256 s).
__global__ __launch_bounds__(256) void kv_partial(
    const unsigned short* __restrict__ PHIK, const unsigned short* __restrict__ Vb,
    float* __restrict__ KVP, float* __restrict__ KSP)
{
    const int bh = blockIdx.x, ch = blockIdx.y;
    const unsigned short* phik = PHIK + ((size_t)bh * SEQ + ch * 256) * 64;
    const unsigned short* v    = Vb   + ((size_t)bh * SEQ + ch * 256) * 64;
    __shared__ float ps[64][68];
    __shared__ float vs[64][68];
    const int tid = threadIdx.x;
    const int tx = tid & 15, ty = tid >> 4;
    const int r0 = ty * 4, c0 = tx * 4;
    float acc[4][4] = {};
    float ks[4] = {};
    for (int sub = 0; sub < 4; ++sub) {
        __syncthreads();
        {
            const int r = tid >> 4, c4 = (tid & 15) * 4;
            #pragma unroll
            for (int it = 0; it < 4; ++it) {
                ushort4 p = *(const ushort4*)&phik[(size_t)(sub * 64 + r + 16 * it) * 64 + c4];
                ushort4 vv = *(const ushort4*)&v[(size_t)(sub * 64 + r + 16 * it) * 64 + c4];
                ps[r + 16 * it][c4 + 0] = b2f(p.x);  ps[r + 16 * it][c4 + 1] = b2f(p.y);
                ps[r + 16 * it][c4 + 2] = b2f(p.z);  ps[r + 16 * it][c4 + 3] = b2f(p.w);
                vs[r + 16 * it][c4 + 0] = b2f(vv.x); vs[r + 16 * it][c4 + 1] = b2f(vv.y);
                vs[r + 16 * it][c4 + 2] = b2f(vv.z); vs[r + 16 * it][c4 + 3] = b2f(vv.w);
            }
        }
        __syncthreads();
        #pragma unroll 4
        for (int s = 0; s < 64; ++s) {
            float4 p4 = *(const float4*)&ps[s][r0];
            float4 v4 = *(const float4*)&vs[s][c0];
            float pa[4] = { p4.x, p4.y, p4.z, p4.w };
            float va[4] = { v4.x, v4.y, v4.z, v4.w };
            #pragma unroll
            for (int a = 0; a < 4; ++a) {
                ks[a] += pa[a];
                #pragma unroll
                for (int bb = 0; bb < 4; ++bb)
                    acc[a][bb] = fmaf(pa[a], va[bb], acc[a][bb]);
            }
        }
    }
    #pragma unroll
    for (int a = 0; a < 4; ++a) {
        float4 o = { acc[a][0], acc[a][1], acc[a][2], acc[a][3] };
        *(float4*)&KVP[((size_t)(bh * 32 + ch) * 64 + r0 + a) * 64 + c0] = o;
    }
    if (tx == 0) {
        #pragma unroll
        for (int a = 0; a < 4; ++a)
            KSP[(bh * 32 + ch) * 64 + r0 + a] = ks[a];
    }
}

__global__ __launch_bounds__(256) void kv_reduce(
    const float* __restrict__ KVP, const float* __restrict__ KSP,
    float* __restrict__ KV, float* __restrict__ KS)
{
    const int bh = blockIdx.x, tid = threadIdx.x;
    for (int e = tid; e < 4096; e += 256) {
        float s = 0.f;
        for (int c = 0; c < 32; ++c) s += KVP[(size_t)(bh * 32 + c) * 4096 + e];
        KV[(size_t)bh * 4096 + e] = s;
    }
    if (tid < 64) {
        float s = 0.f;
        for (int c = 0; c < 32; ++c) s += KSP[(bh * 32 + c) * 64 + tid];
        KS[bh * 64 + tid] = s;
    }
}

// ---------------- out_attn = (phi_q@kv)/(phi_q@ksum+eps) -> bf16, 4x4 tiled --
__global__ __launch_bounds__(256) void attn_out(
    const unsigned short* __restrict__ PHIQ, const float* __restrict__ KV,
    const float* __restrict__ KS, unsigned short* __restrict__ OAb)
{
    const int bh = blockIdx.x;
    const int b = bh >> 3, h = bh & 7;
    __shared__ float kvs[64][68];
    __shared__ float pqs[64][65];
    __shared__ float kss[64];
    const int tid = threadIdx.x;
    const int tx = tid & 15, ty = tid >> 4;
    const int s0 = blockIdx.y * 64;
    {
        const int r = tid >> 4, c4 = (tid & 15) * 4;
        #pragma unroll
        for (int it = 0; it < 4; ++it) {
            float4 kvv = *(const float4*)&KV[(size_t)bh * 4096 + (size_t)(r + 16 * it) * 64 + c4];
            ushort4 pq = *(const ushort4*)&PHIQ[((size_t)bh * SEQ + s0 + r + 16 * it) * 64 + c4];
            *(float4*)&kvs[r + 16 * it][c4] = kvv;
            pqs[r + 16 * it][c4 + 0] = b2f(pq.x); pqs[r + 16 * it][c4 + 1] = b2f(pq.y);
            pqs[r + 16 * it][c4 + 2] = b2f(pq.z); pqs[r + 16 * it][c4 + 3] = b2f(pq.w);
        }
        if (tid < 64) kss[tid] = KS[bh * 64 + tid];
    }
    __syncthreads();
    const int r0 = ty * 4, c0 = tx * 4;
    float num[4][4] = {};
    float den[4] = { 1e-6f, 1e-6f, 1e-6f, 1e-6f };
    #pragma unroll 4
    for (int i = 0; i < 64; ++i) {
        float pr[4] = { pqs[r0][i], pqs[r0 + 1][i], pqs[r0 + 2][i], pqs[r0 + 3][i] };
        float4 kv4 = *(const float4*)&kvs[i][c0];
        float kva[4] = { kv4.x, kv4.y, kv4.z, kv4.w };
        float ksv = kss[i];
        #pragma unroll
        for (int a = 0; a < 4; ++a) {
            den[a] = fmaf(pr[a], ksv, den[a]);
            #pragma unroll
            for (int bb = 0; bb < 4; ++bb)
                num[a][bb] = fmaf(pr[a], kva[bb], num[a][bb]);
        }
    }
    #pragma unroll
    for (int a = 0; a < 4; ++a) {
        const float inv = 1.0f / den[a];
        ushort4 o = { f2b(num[a][0] * inv), f2b(num[a][1] * inv),
                      f2b(num[a][2] * inv), f2b(num[a][3] * inv) };
        const int s = s0 + r0 + a;
        *(ushort4*)&OAb[((size_t)(b * SEQ + s)) * 512 + h * 64 + c0] = o;
    }
}

extern "C" void kernel_launch(void* const* d_in, const int* in_sizes, int n_in,
                              void* d_out, int out_size, void* d_ws, size_t ws_size,
                              hipStream_t stream)
{
    (void)in_sizes; (void)n_in; (void)out_size; (void)ws_size;
    const float* x   = (const float*)d_in[0];
    const float* Wq  = (const float*)d_in[1];
    const float* bq  = (const float*)d_in[2];
    const float* Wk  = (const float*)d_in[3];
    const float* bk  = (const float*)d_in[4];
    const float* Wv  = (const float*)d_in[5];
    const float* bv  = (const float*)d_in[6];
    const float* Wp  = (const float*)d_in[7];
    const float* bp  = (const float*)d_in[8];
    const float* gq  = (const float*)d_in[9];
    const float* bbq = (const float*)d_in[10];
    const float* gk  = (const float*)d_in[11];
    const float* bbk = (const float*)d_in[12];
    const float* qG1 = (const float*)d_in[13];
    const float* qG2 = (const float*)d_in[14];
    const float* kG1 = (const float*)d_in[15];
    const float* kG2 = (const float*)d_in[16];

    unsigned short* PHIQ = (unsigned short*)d_ws;       // 16,777,216 us (32 MB)
    unsigned short* PHIK = PHIQ + 16777216;             // 32 MB
    unsigned short* Vb   = PHIK + 16777216;             // 32 MB
    unsigned short* xb   = Vb   + 16777216;             // 32 MB
    unsigned short* OAb  = xb   + 16777216;             // 32 MB
    unsigned short* WTf  = OAb  + 16777216;             // 2560*512 us (2.5 MB)
    unsigned short* WTp  = WTf  + 2560 * 512;           // 512*512 us (0.5 MB)
    float* cvec = (float*)(WTp + 262144);               // 2,560 f
    float* KVP  = cvec + 2560;                          // 4,194,304 f (16 MB)
    float* KSP  = KVP + 4194304;                        // 65,536 f
    float* KV   = KSP + 65536;                          // 131,072 f
    float* KS   = KV + 131072;                          // 2,048 f  (total ~180 MB)
    float* out  = (float*)d_out;

    hipLaunchKernelGGL(convert_x, dim3(8192), dim3(256), 0, stream, x, xb);
    hipLaunchKernelGGL(convert_wT, dim3(16, 16, 2), dim3(256), 0, stream,
                       Wv, Wp, WTf, WTp);
    hipLaunchKernelGGL(precompute_wc, dim3(33), dim3(256), 0, stream,
                       Wq, bq, Wk, bk, bv, gq, bbq, gk, bbk,
                       qG1, qG2, kG1, kG2, WTf, cvec);
    hipLaunchKernelGGL(gemm_mfma_fused, dim3(256, 20), dim3(256), 0, stream,
                       xb, WTf, cvec, PHIQ, PHIK, Vb);
    hipLaunchKernelGGL(kv_partial, dim3(32, 32), dim3(256), 0, stream,
                       PHIK, Vb, KVP, KSP);
    hipLaunchKernelGGL(kv_reduce, dim3(32), dim3(256), 0, stream, KVP, KSP, KV, KS);
    hipLaunchKernelGGL(attn_out, dim3(32, 128), dim3(256), 0, stream,
                       PHIQ, KV, KS, OAb);
    hipLaunchKernelGGL(gemm_mfma_final, dim3(256, 4), dim3(256), 0, stream,
                       OAb, WTp, bp, out);
}

// Round 6
// 428.470 us; speedup vs baseline: 1.3455x; 1.3455x over previous
//
#include <hip/hip_runtime.h>
#include <hip/hip_bf16.h>

// MHSA_69621419869026 — p=4 sketch linear attention, MI355X gfx950.
// Round 6: fix precompute_wc launch-shape starvation (33 blocks @1.4% occ,
// 199 us -> grid (33,16) = 528 blocks). Rest identical to round 5:
// fused GEMM x@[Aq1|Aq2|Ak1|Ak2|Wv] with phi epilogue, bf16 phi/v.
// Dims: B=4 S=8192 D=512 H=8 HD=R=64, N=B*S=32768.

#define SEQ 8192

typedef __attribute__((ext_vector_type(8))) short bf16x8;
typedef __attribute__((ext_vector_type(4))) float f32x4;

__device__ __forceinline__ unsigned short f2b(float f) {
    union { float f; unsigned int i; } v; v.f = f;
    unsigned int r = v.i + 0x7fffu + ((v.i >> 16) & 1u);   // RNE
    return (unsigned short)(r >> 16);
}
__device__ __forceinline__ float b2f(unsigned short u) {
    union { unsigned int i; float f; } v; v.i = ((unsigned int)u) << 16; return v.f;
}

#if __has_builtin(__builtin_amdgcn_global_load_lds)
#define ASYNC_CP 1
#endif

__device__ __forceinline__ void cp16(const unsigned short* g, unsigned short* l) {
#ifdef ASYNC_CP
    __builtin_amdgcn_global_load_lds(
        (const __attribute__((address_space(1))) unsigned int*)g,
        (__attribute__((address_space(3))) unsigned int*)l, 16, 0, 0);
#endif
}

// ---------------- pre-pass: x fp32 -> bf16 (RNE) ----------------------------
__global__ __launch_bounds__(256) void convert_x(
    const float* __restrict__ x, unsigned short* __restrict__ xb)
{
    size_t i = ((size_t)blockIdx.x * 256 + threadIdx.x) * 8;
    float4 a = *(const float4*)&x[i];
    float4 b = *(const float4*)&x[i + 4];
    ushort4 o1 = { f2b(a.x), f2b(a.y), f2b(a.z), f2b(a.w) };
    ushort4 o2 = { f2b(b.x), f2b(b.y), f2b(b.z), f2b(b.w) };
    *(ushort4*)&xb[i]     = o1;
    *(ushort4*)&xb[i + 4] = o2;
}

// ---------------- pre-pass: Wv/Wp fp32 [k][n] -> bf16 [n][k] -----------------
__global__ __launch_bounds__(256) void convert_wT(
    const float* __restrict__ Wv, const float* __restrict__ Wp,
    unsigned short* __restrict__ WTf, unsigned short* __restrict__ WTp)
{
    const int z = blockIdx.z;
    const float* W = (z == 0) ? Wv : Wp;
    unsigned short* O = (z == 0) ? (WTf + (size_t)2048 * 512) : WTp;
    __shared__ float t[32][33];
    const int tid = threadIdx.x;
    const int tx = tid & 31, ty = tid >> 5;
    const int k0 = blockIdx.x * 32, n0 = blockIdx.y * 32;
    #pragma unroll
    for (int i = 0; i < 4; ++i)
        t[ty + 8 * i][tx] = W[(size_t)(k0 + ty + 8 * i) * 512 + n0 + tx];
    __syncthreads();
    #pragma unroll
    for (int i = 0; i < 4; ++i)
        O[(size_t)(n0 + ty + 8 * i) * 512 + k0 + tx] = f2b(t[tx][ty + 8 * i]);
}

// ---------------- weight composition: WC = gamma * W_z[:,h-block] @ G --------
// grid (33, 16). x: 0..31 -> (zz = bi>>4, h = (bi>>1)&7, p = bi&1); 32 -> bv copy.
// y: 32-wide k-slice. Per block: 256 thr, rr = tid&63, kg = tid>>6.
__global__ __launch_bounds__(256) void precompute_wc(
    const float* __restrict__ Wq, const float* __restrict__ bq,
    const float* __restrict__ Wk, const float* __restrict__ bk,
    const float* __restrict__ bv,
    const float* __restrict__ gq, const float* __restrict__ bbq,
    const float* __restrict__ gk, const float* __restrict__ bbk,
    const float* __restrict__ qG1, const float* __restrict__ qG2,
    const float* __restrict__ kG1, const float* __restrict__ kG2,
    unsigned short* __restrict__ WTf, float* __restrict__ cvec)
{
    const int bi = blockIdx.x;
    const int tid = threadIdx.x;
    if (bi == 32) {
        if (blockIdx.y == 0)
            for (int i = tid; i < 512; i += 256) cvec[2048 + i] = bv[i];
        return;
    }
    const int zz = bi >> 4, h = (bi >> 1) & 7, p = bi & 1;
    const float* W    = zz ? Wk : Wq;
    const float* bias = zz ? bk : bq;
    const float* G    = zz ? (p ? kG2 : kG1) : (p ? qG2 : qG1);
    const float  gamma = zz ? gk[0] : gq[0];
    const float  beta  = zz ? bbk[0] : bbq[0];

    __shared__ float Gs[64][65];
    for (int i = tid; i < 4096; i += 256) Gs[i >> 6][i & 63] = G[i];
    __syncthreads();

    const int rr = tid & 63, kg = tid >> 6;
    const int jc = zz * 1024 + h * 128 + rr * 2 + p;
    const int k0 = blockIdx.y * 32;
    for (int k = k0 + kg; k < k0 + 32; k += 4) {
        float s = 0.f;
        const float* wrow = &W[(size_t)k * 512 + h * 64];
        #pragma unroll 8
        for (int j = 0; j < 64; ++j) s = fmaf(wrow[j], Gs[j][rr], s);
        WTf[(size_t)jc * 512 + k] = f2b(gamma * s);
    }
    if (kg == 0 && blockIdx.y == 0) {
        float cb = 0.f, cg = 0.f;
        #pragma unroll 8
        for (int j = 0; j < 64; ++j) {
            cb = fmaf(bias[h * 64 + j], Gs[j][rr], cb);
            cg += Gs[j][rr];
        }
        cvec[jc] = gamma * cb + beta * cg;
    }
}

// ---------------- fused MFMA GEMM: U = x @ WC, phi/v epilogue ----------------
// grid (256 token-tiles, 20 j-tiles). 128x128 tile, 4 waves.
// jc in [0,1024): phi_q pairs; [1024,2048): phi_k pairs; [2048,2560): v.
__global__ __launch_bounds__(256) void gemm_mfma_fused(
    const unsigned short* __restrict__ xb,
    const unsigned short* __restrict__ WTf,
    const float* __restrict__ cvec,
    unsigned short* __restrict__ PHIQ, unsigned short* __restrict__ PHIK,
    unsigned short* __restrict__ Vb)
{
    __shared__ __align__(16) unsigned short As[128 * 32];
    __shared__ __align__(16) unsigned short Bs[128 * 32];

    const int tid = threadIdx.x;
    const int w = tid >> 6, lane = tid & 63;
    const int n0 = blockIdx.x * 128;
    const int j0 = blockIdx.y * 128;
    const int wr = w >> 1, wc = w & 1;

    const int r0 = w * 32 + (lane >> 2);
    const int kq = (lane & 3) * 8;
    const unsigned short* gA = &xb[(size_t)(n0 + r0) * 512 + kq];
    const unsigned short* gB = &WTf[(size_t)(j0 + r0) * 512 + kq];
    unsigned short* lA = &As[(w * 32) * 32];
    unsigned short* lB = &Bs[(w * 32) * 32];

    f32x4 acc[4][4];
    #pragma unroll
    for (int i = 0; i < 4; ++i)
        #pragma unroll
        for (int j = 0; j < 4; ++j) { acc[i][j] = (f32x4){0.f, 0.f, 0.f, 0.f}; }

    for (int k0 = 0; k0 < 512; k0 += 32) {
        __syncthreads();
#ifdef ASYNC_CP
        cp16(gA + k0, lA);
        cp16(gA + 16 * 512 + k0, lA + 16 * 32);
        cp16(gB + k0, lB);
        cp16(gB + 16 * 512 + k0, lB + 16 * 32);
#else
        { uint4 v = *(const uint4*)(gA + k0);            *(uint4*)(lA + (size_t)lane * 8) = v; }
        { uint4 v = *(const uint4*)(gA + 16 * 512 + k0); *(uint4*)(lA + 16 * 32 + (size_t)lane * 8) = v; }
        { uint4 v = *(const uint4*)(gB + k0);            *(uint4*)(lB + (size_t)lane * 8) = v; }
        { uint4 v = *(const uint4*)(gB + 16 * 512 + k0); *(uint4*)(lB + 16 * 32 + (size_t)lane * 8) = v; }
#endif
        __syncthreads();

        bf16x8 af[4], bfr[4];
        #pragma unroll
        for (int i = 0; i < 4; ++i) {
            af[i]  = *(const bf16x8*)&As[(wr * 64 + i * 16 + (lane & 15)) * 32 + (lane >> 4) * 8];
            bfr[i] = *(const bf16x8*)&Bs[(wc * 64 + i * 16 + (lane & 15)) * 32 + (lane >> 4) * 8];
        }
        #pragma unroll
        for (int mi = 0; mi < 4; ++mi)
            #pragma unroll
            for (int ni = 0; ni < 4; ++ni)
                acc[mi][ni] = __builtin_amdgcn_mfma_f32_16x16x32_bf16(
                    af[mi], bfr[ni], acc[mi][ni], 0, 0, 0);
    }

    // epilogue. jcol parity == lane&1; a 128-col tile sits in exactly one group
    // (q-head / k-head / v) so branches are wave-uniform.
    #pragma unroll
    for (int ni = 0; ni < 4; ++ni) {
        const int jcol = j0 + wc * 64 + ni * 16 + (lane & 15);
        const float cv = cvec[jcol];
        if (jcol < 2048) {                       // phi path
            const int zq = jcol >> 10;           // 0 = q, 1 = k
            const int lc = jcol & 1023;
            const int h = lc >> 7, rr = (lc >> 1) & 63;
            unsigned short* dst = zq ? PHIK : PHIQ;
            #pragma unroll
            for (int mi = 0; mi < 4; ++mi) {
                #pragma unroll
                for (int r = 0; r < 4; ++r) {
                    float u = acc[mi][ni][r] + cv;
                    float up = __shfl_xor(u, 1);
                    float hh = 0.125f * u * up;
                    float phi = hh * hh;
                    if ((lane & 1) == 0) {
                        const int t = n0 + wr * 64 + mi * 16 + (lane >> 4) * 4 + r;
                        const int b = t >> 13, s = t & (SEQ - 1);
                        dst[((size_t)(b * 8 + h) * SEQ + s) * 64 + rr] = f2b(phi);
                    }
                }
            }
        } else {                                 // v path
            const int n = jcol - 2048;
            const int h = n >> 6, hd = n & 63;
            #pragma unroll
            for (int mi = 0; mi < 4; ++mi) {
                #pragma unroll
                for (int r = 0; r < 4; ++r) {
                    const int t = n0 + wr * 64 + mi * 16 + (lane >> 4) * 4 + r;
                    const int b = t >> 13, s = t & (SEQ - 1);
                    Vb[((size_t)(b * 8 + h) * SEQ + s) * 64 + hd] =
                        f2b(acc[mi][ni][r] + cv);
                }
            }
        }
    }
}

// ---------------- bf16 MFMA GEMM: final projection ---------------------------
__global__ __launch_bounds__(256) void gemm_mfma_final(
    const unsigned short* __restrict__ Ab,
    const unsigned short* __restrict__ WTp,
    const float* __restrict__ bias, float* __restrict__ out)
{
    __shared__ __align__(16) unsigned short As[128 * 32];
    __shared__ __align__(16) unsigned short Bs[128 * 32];

    const int tid = threadIdx.x;
    const int w = tid >> 6, lane = tid & 63;
    const int n0 = blockIdx.x * 128;
    const int j0 = blockIdx.y * 128;
    const int wr = w >> 1, wc = w & 1;

    const int r0 = w * 32 + (lane >> 2);
    const int kq = (lane & 3) * 8;
    const unsigned short* gA = &Ab[(size_t)(n0 + r0) * 512 + kq];
    const unsigned short* gB = &WTp[(size_t)(j0 + r0) * 512 + kq];
    unsigned short* lA = &As[(w * 32) * 32];
    unsigned short* lB = &Bs[(w * 32) * 32];

    f32x4 acc[4][4];
    #pragma unroll
    for (int i = 0; i < 4; ++i)
        #pragma unroll
        for (int j = 0; j < 4; ++j) { acc[i][j] = (f32x4){0.f, 0.f, 0.f, 0.f}; }

    for (int k0 = 0; k0 < 512; k0 += 32) {
        __syncthreads();
#ifdef ASYNC_CP
        cp16(gA + k0, lA);
        cp16(gA + 16 * 512 + k0, lA + 16 * 32);
        cp16(gB + k0, lB);
        cp16(gB + 16 * 512 + k0, lB + 16 * 32);
#else
        { uint4 v = *(const uint4*)(gA + k0);            *(uint4*)(lA + (size_t)lane * 8) = v; }
        { uint4 v = *(const uint4*)(gA + 16 * 512 + k0); *(uint4*)(lA + 16 * 32 + (size_t)lane * 8) = v; }
        { uint4 v = *(const uint4*)(gB + k0);            *(uint4*)(lB + (size_t)lane * 8) = v; }
        { uint4 v = *(const uint4*)(gB + 16 * 512 + k0); *(uint4*)(lB + 16 * 32 + (size_t)lane * 8) = v; }
#endif
        __syncthreads();

        bf16x8 af[4], bfr[4];
        #pragma unroll
        for (int i = 0; i < 4; ++i) {
            af[i]  = *(const bf16x8*)&As[(wr * 64 + i * 16 + (lane & 15)) * 32 + (lane >> 4) * 8];
            bfr[i] = *(const bf16x8*)&Bs[(wc * 64 + i * 16 + (lane & 15)) * 32 + (lane >> 4) * 8];
        }
        #pragma unroll
        for (int mi = 0; mi < 4; ++mi)
            #pragma unroll
            for (int ni = 0; ni < 4; ++ni)
                acc[mi][ni] = __builtin_amdgcn_mfma_f32_16x16x32_bf16(
                    af[mi], bfr[ni], acc[mi][ni], 0, 0, 0);
    }

    #pragma unroll
    for (int ni = 0; ni < 4; ++ni) {
        const int jcol = j0 + wc * 64 + ni * 16 + (lane & 15);
        const float bvv = bias[jcol];
        #pragma unroll
        for (int mi = 0; mi < 4; ++mi) {
            #pragma unroll
            for (int r = 0; r < 4; ++r) {
                const int t = n0 + wr * 64 + mi * 16 + (lane >> 4) * 4 + r;
                out[(size_t)t * 512 + jcol] = acc[mi][ni][r] + bvv;
            }
        }
    }
}

// ---------------- kv = phi_k^T @ v, ksum (split-S partials), 4x4 tiled -------
__global__ __launch_bounds__(256) void kv_partial(
    const unsigned short* __restrict__ PHIK, const unsigned short* __restrict__ Vb,
    float* __restrict__ KVP, float* __restrict__ KSP)
{
    const int bh = blockIdx.x, ch = blockIdx.y;
    const unsigned short* phik = PHIK + ((size_t)bh * SEQ + ch * 256) * 64;
    const unsigned short* v    = Vb   + ((size_t)bh * SEQ + ch * 256) * 64;
    __shared__ float ps[64][68];
    __shared__ float vs[64][68];
    const int tid = threadIdx.x;
    const int tx = tid & 15, ty = tid >> 4;
    const int r0 = ty * 4, c0 = tx * 4;
    float acc[4][4] = {};
    float ks[4] = {};
    for (int sub = 0; sub < 4; ++sub) {
        __syncthreads();
        {
            const int r = tid >> 4, c4 = (tid & 15) * 4;
            #pragma unroll
            for (int it = 0; it < 4; ++it) {
                ushort4 p = *(const ushort4*)&phik[(size_t)(sub * 64 + r + 16 * it) * 64 + c4];
                ushort4 vv = *(const ushort4*)&v[(size_t)(sub * 64 + r + 16 * it) * 64 + c4];
                ps[r + 16 * it][c4 + 0] = b2f(p.x);  ps[r + 16 * it][c4 + 1] = b2f(p.y);
                ps[r + 16 * it][c4 + 2] = b2f(p.z);  ps[r + 16 * it][c4 + 3] = b2f(p.w);
                vs[r + 16 * it][c4 + 0] = b2f(vv.x); vs[r + 16 * it][c4 + 1] = b2f(vv.y);
                vs[r + 16 * it][c4 + 2] = b2f(vv.z); vs[r + 16 * it][c4 + 3] = b2f(vv.w);
            }
        }
        __syncthreads();
        #pragma unroll 4
        for (int s = 0; s < 64; ++s) {
            float4 p4 = *(const float4*)&ps[s][r0];
            float4 v4 = *(const float4*)&vs[s][c0];
            float pa[4] = { p4.x, p4.y, p4.z, p4.w };
            float va[4] = { v4.x, v4.y, v4.z, v4.w };
            #pragma unroll
            for (int a = 0; a < 4; ++a) {
                ks[a] += pa[a];
                #pragma unroll
                for (int bb = 0; bb < 4; ++bb)
                    acc[a][bb] = fmaf(pa[a], va[bb], acc[a][bb]);
            }
        }
    }
    #pragma unroll
    for (int a = 0; a < 4; ++a) {
        float4 o = { acc[a][0], acc[a][1], acc[a][2], acc[a][3] };
        *(float4*)&KVP[((size_t)(bh * 32 + ch) * 64 + r0 + a) * 64 + c0] = o;
    }
    if (tx == 0) {
        #pragma unroll
        for (int a = 0; a < 4; ++a)
            KSP[(bh * 32 + ch) * 64 + r0 + a] = ks[a];
    }
}

__global__ __launch_bounds__(256) void kv_reduce(
    const float* __restrict__ KVP, const float* __restrict__ KSP,
    float* __restrict__ KV, float* __restrict__ KS)
{
    const int bh = blockIdx.x, tid = threadIdx.x;
    for (int e = tid; e < 4096; e += 256) {
        float s = 0.f;
        for (int c = 0; c < 32; ++c) s += KVP[(size_t)(bh * 32 + c) * 4096 + e];
        KV[(size_t)bh * 4096 + e] = s;
    }
    if (tid < 64) {
        float s = 0.f;
        for (int c = 0; c < 32; ++c) s += KSP[(bh * 32 + c) * 64 + tid];
        KS[bh * 64 + tid] = s;
    }
}

// ---------------- out_attn = (phi_q@kv)/(phi_q@ksum+eps) -> bf16, 4x4 tiled --
__global__ __launch_bounds__(256) void attn_out(
    const unsigned short* __restrict__ PHIQ, const float* __restrict__ KV,
    const float* __restrict__ KS, unsigned short* __restrict__ OAb)
{
    const int bh = blockIdx.x;
    const int b = bh >> 3, h = bh & 7;
    __shared__ float kvs[64][68];
    __shared__ float pqs[64][65];
    __shared__ float kss[64];
    const int tid = threadIdx.x;
    const int tx = tid & 15, ty = tid >> 4;
    const int s0 = blockIdx.y * 64;
    {
        const int r = tid >> 4, c4 = (tid & 15) * 4;
        #pragma unroll
        for (int it = 0; it < 4; ++it) {
            float4 kvv = *(const float4*)&KV[(size_t)bh * 4096 + (size_t)(r + 16 * it) * 64 + c4];
            ushort4 pq = *(const ushort4*)&PHIQ[((size_t)bh * SEQ + s0 + r + 16 * it) * 64 + c4];
            *(float4*)&kvs[r + 16 * it][c4] = kvv;
            pqs[r + 16 * it][c4 + 0] = b2f(pq.x); pqs[r + 16 * it][c4 + 1] = b2f(pq.y);
            pqs[r + 16 * it][c4 + 2] = b2f(pq.z); pqs[r + 16 * it][c4 + 3] = b2f(pq.w);
        }
        if (tid < 64) kss[tid] = KS[bh * 64 + tid];
    }
    __syncthreads();
    const int r0 = ty * 4, c0 = tx * 4;
    float num[4][4] = {};
    float den[4] = { 1e-6f, 1e-6f, 1e-6f, 1e-6f };
    #pragma unroll 4
    for (int i = 0; i < 64; ++i) {
        float pr[4] = { pqs[r0][i], pqs[r0 + 1][i], pqs[r0 + 2][i], pqs[r0 + 3][i] };
        float4 kv4 = *(const float4*)&kvs[i][c0];
        float kva[4] = { kv4.x, kv4.y, kv4.z, kv4.w };
        float ksv = kss[i];
        #pragma unroll
        for (int a = 0; a < 4; ++a) {
            den[a] = fmaf(pr[a], ksv, den[a]);
            #pragma unroll
            for (int bb = 0; bb < 4; ++bb)
                num[a][bb] = fmaf(pr[a], kva[bb], num[a][bb]);
        }
    }
    #pragma unroll
    for (int a = 0; a < 4; ++a) {
        const float inv = 1.0f / den[a];
        ushort4 o = { f2b(num[a][0] * inv), f2b(num[a][1] * inv),
                      f2b(num[a][2] * inv), f2b(num[a][3] * inv) };
        const int s = s0 + r0 + a;
        *(ushort4*)&OAb[((size_t)(b * SEQ + s)) * 512 + h * 64 + c0] = o;
    }
}

extern "C" void kernel_launch(void* const* d_in, const int* in_sizes, int n_in,
                              void* d_out, int out_size, void* d_ws, size_t ws_size,
                              hipStream_t stream)
{
    (void)in_sizes; (void)n_in; (void)out_size; (void)ws_size;
    const float* x   = (const float*)d_in[0];
    const float* Wq  = (const float*)d_in[1];
    const float* bq  = (const float*)d_in[2];
    const float* Wk  = (const float*)d_in[3];
    const float* bk  = (const float*)d_in[4];
    const float* Wv  = (const float*)d_in[5];
    const float* bv  = (const float*)d_in[6];
    const float* Wp  = (const float*)d_in[7];
    const float* bp  = (const float*)d_in[8];
    const float* gq  = (const float*)d_in[9];
    const float* bbq = (const float*)d_in[10];
    const float* gk  = (const float*)d_in[11];
    const float* bbk = (const float*)d_in[12];
    const float* qG1 = (const float*)d_in[13];
    const float* qG2 = (const float*)d_in[14];
    const float* kG1 = (const float*)d_in[15];
    const float* kG2 = (const float*)d_in[16];

    unsigned short* PHIQ = (unsigned short*)d_ws;       // 32 MB
    unsigned short* PHIK = PHIQ + 16777216;             // 32 MB
    unsigned short* Vb   = PHIK + 16777216;             // 32 MB
    unsigned short* xb   = Vb   + 16777216;             // 32 MB
    unsigned short* OAb  = xb   + 16777216;             // 32 MB
    unsigned short* WTf  = OAb  + 16777216;             // 2.5 MB
    unsigned short* WTp  = WTf  + 2560 * 512;           // 0.5 MB
    float* cvec = (float*)(WTp + 262144);               // 2,560 f
    float* KVP  = cvec + 2560;                          // 16 MB
    float* KSP  = KVP + 4194304;
    float* KV   = KSP + 65536;
    float* KS   = KV + 131072;
    float* out  = (float*)d_out;

    hipLaunchKernelGGL(convert_x, dim3(8192), dim3(256), 0, stream, x, xb);
    hipLaunchKernelGGL(convert_wT, dim3(16, 16, 2), dim3(256), 0, stream,
                       Wv, Wp, WTf, WTp);
    hipLaunchKernelGGL(precompute_wc, dim3(33, 16), dim3(256), 0, stream,
                       Wq, bq, Wk, bk, bv, gq, bbq, gk, bbk,
                       qG1, qG2, kG1, kG2, WTf, cvec);
    hipLaunchKernelGGL(gemm_mfma_fused, dim3(256, 20), dim3(256), 0, stream,
                       xb, WTf, cvec, PHIQ, PHIK, Vb);
    hipLaunchKernelGGL(kv_partial, dim3(32, 32), dim3(256), 0, stream,
                       PHIK, Vb, KVP, KSP);
    hipLaunchKernelGGL(kv_reduce, dim3(32), dim3(256), 0, stream, KVP, KSP, KV, KS);
    hipLaunchKernelGGL(attn_out, dim3(32, 128), dim3(256), 0, stream,
                       PHIQ, KV, KS, OAb);
    hipLaunchKernelGGL(gemm_mfma_final, dim3(256, 4), dim3(256), 0, stream,
                       OAb, WTp, bp, out);
}